// Round 4
// baseline (424.039 us; speedup 1.0000x reference)
//
#include <hip/hip_runtime.h>

// PiecewiseLinearEmbedding: out[i,t,:] = cumsum(W, axis=1)[:, x[i,t]] + b
//   x: (8192,200) int32 in [0,128]   W: (64,129) fp32   b: (64,) fp32
//   out: (8192,200,64) fp32 = 419.4 MB  -> pure streaming-write bound.
//
// R8: FEW LONG SEQUENTIAL STREAMS (fill-mimic occupancy).
// Evidence chain: R5 nt=neutral (no write-allocate fetch), R6 fusion=-3us
// (no launch overhead), R7 dense grid-stride sweep=-7us (macro schedule
// ~irrelevant). Embed stuck at ~140us = 2.9 TB/s stores; the poison fill
// does 6.2 TB/s on the SAME arena at OccupancyPercent ~10 (~3 waves/CU,
// ~800 waves device-wide). We ran 8192 store streams (32 waves/CU); at
// ~128 HBM channels that is ~64 streams/channel, each touching 1 KB at
// 8 MB stride -> row-activate per burst, the classic ~2x write BW loss.
// The fill presents ~6 sequential streams/channel. Stream COUNT is the
// one structural variable untouched by R5-R7.
// This round: 256 blocks x 256 thr (1 block/CU, 4 waves/CU), each WAVE
// owns a contiguous 400 KB span walked sequentially in 1 KB stores,
// 16-deep batched so chained LDS latency (~240cy) hides under the
// HBM-paced store drain (vmcnt backpressure = flow control, like fill).
// Predict: embed 140 -> ~75-85, dur 413 -> ~345-360. If unchanged:
// stream theory dead -> next round double-store instrumentation (push
// embed past the fills into rocprof top-5 to finally SEE its counters).
// If >=440: latency exposure -> revert occupancy, then instrument.

constexpr int F1   = 129;              // NUM_FEATURE + 1 bins
constexpr int D    = 64;               // VECTOR_DIM
constexpr int ROWS = 8192 * 200;       // 1,638,400 lookup rows
constexpr int TBL_F = F1 * D;          // 8,256 floats (33,024 B)
constexpr int TBL4  = TBL_F / 4;       // 2,064 float4

constexpr int BLOCKS = 256;            // 1 block/CU
constexpr int TPB    = 256;            // 4 waves/CU ~= fill's regime
constexpr int ROWS_PER_BLOCK = ROWS / BLOCKS;          // 6,400
constexpr int Q_PER_BLOCK    = ROWS_PER_BLOCK * D / 4; // 102,400 float4
constexpr int Q_PER_WAVE     = Q_PER_BLOCK / 4;        // 25,600 float4 (400 KB)
constexpr int ROWS_PER_WAVE  = ROWS_PER_BLOCK / 4;     // 1,600
constexpr int ITERS          = Q_PER_WAVE / 64;        // 400 stores/lane-col
constexpr int BATCH          = 16;                     // 16 KB per wave burst

typedef float floatx4 __attribute__((ext_vector_type(4)));

__global__ __launch_bounds__(TPB) void embed_fused_kernel(
        const int*   __restrict__ x,
        const float* __restrict__ W,
        const float* __restrict__ b,
        float*       __restrict__ out) {
    __shared__ floatx4 lds_tbl[TBL4];          // 33,024 B, j-major table
    __shared__ int     lds_x[ROWS_PER_BLOCK];  // 25,600 B  (58,624 B total)
    float* tblf = (float*)lds_tbl;

    // Stage this block's 6400 x values (25 coalesced 1 KB rounds).
    const int row0 = blockIdx.x * ROWS_PER_BLOCK;
    for (int i = threadIdx.x; i < ROWS_PER_BLOCK; i += TPB)
        lds_x[i] = x[row0 + i];

    // Wave 0: build the cumsum table. Lane d scans W row d from global
    // (L2-hot 33 KB); loads batched 8-deep so the only serial chain is
    // 129 v_add_f32. LDS writes [j*64+d]: lanes span d at fixed j ->
    // bank d%32, 2-way, conflict-free.
    if (threadIdx.x < D) {
        const int d = threadIdx.x;
        const float* wrow = W + d * F1;
        float acc = b[d];
        int j = 0;
#pragma unroll 1
        for (int c = 0; c < 16; ++c) {         // 16 chunks of 8 = 128
            float v[8];
#pragma unroll
            for (int i = 0; i < 8; ++i) v[i] = wrow[j + i];   // independent loads
#pragma unroll
            for (int i = 0; i < 8; ++i) { acc += v[i]; tblf[(j + i) * D + d] = acc; }
            j += 8;
        }
        acc += wrow[128];                      // tail bin
        tblf[128 * D + d] = acc;
    }
    __syncthreads();

    // Hot loop: each wave walks its own contiguous 400 KB span in 1 KB
    // stores, 16-deep batches. Gather is the same conflict-free pattern:
    // 16 lanes/addr broadcast on lds_x; lds_tbl b128 uniform over banks.
    const int wave = threadIdx.x >> 6;
    const int lane = threadIdx.x & 63;
    const int quad = lane & 15;
    const int xrow0 = wave * ROWS_PER_WAVE + (lane >> 4);  // +4 per iter
    floatx4* wout = (floatx4*)out
                  + (size_t)blockIdx.x * Q_PER_BLOCK
                  + wave * Q_PER_WAVE + lane;

#pragma unroll 1
    for (int i = 0; i < ITERS; i += BATCH) {
        floatx4 v[BATCH];
#pragma unroll
        for (int u = 0; u < BATCH; ++u) {
            int xi = lds_x[xrow0 + (i + u) * 4];     // broadcast read
            v[u]   = lds_tbl[xi * 16 + quad];        // conflict-free b128
        }
#pragma unroll
        for (int u = 0; u < BATCH; ++u)
            wout[(i + u) * 64] = v[u];               // sequential 1 KB stores
    }
}

extern "C" void kernel_launch(void* const* d_in, const int* in_sizes, int n_in,
                              void* d_out, int out_size, void* d_ws, size_t ws_size,
                              hipStream_t stream) {
    const int*   x = (const int*)  d_in[0];
    const float* W = (const float*)d_in[1];
    const float* b = (const float*)d_in[2];
    float* out = (float*)d_out;
    (void)d_ws; (void)ws_size;

    embed_fused_kernel<<<BLOCKS, TPB, 0, stream>>>(x, W, b, out);
}